// Round 3
// baseline (234.638 us; speedup 1.0000x reference)
//
#include <hip/hip_runtime.h>

#define BATCH 2
#define SEQ   384
#define HID   128
#define TABLE (2 * SEQ + 1)   // 769
#define TPB   8               // t-rows per block in precompute

typedef unsigned int   uint32;
typedef unsigned short ushort16;
typedef float  vfloat4 __attribute__((ext_vector_type(4)));
typedef uint32 vuint4  __attribute__((ext_vector_type(4)));

// ws layout:
//   V  (bf16) 8*TABLE*HID  = 1.50 MiB   bf16(T0[d] + T1[d-sk] + b)
//   W2 (bf16) 8*TABLE*HID  = 1.50 MiB   bf16(T2[d] + T3[d-sk])
//   T  (f32)  4*TABLE*HID  = 1.50 MiB   per-table GEMM results (f32 intermediate)
//   Wt (f32)  4*HID*HID    = 256 KiB
// V+W2 = 3.0 MiB -> fully L2-resident per XCD (4 MiB): gather reads at L2 tier.

// bf16 helpers: bf16 is the high half of fp32 — unpack is exact.
__device__ __forceinline__ float blo(uint32 u) { return __uint_as_float(u << 16); }
__device__ __forceinline__ float bhi(uint32 u) { return __uint_as_float(u & 0xFFFF0000u); }
__device__ __forceinline__ ushort16 f2bf_rn(float f) {
    uint32 u = __float_as_uint(f);
    u += 0x7FFFu + ((u >> 16) & 1u);   // round-to-nearest-even
    return (ushort16)(u >> 16);
}

// Kernel 0: Wt[tab][f][h] = W[h][tab*HID + f]   (W row-major [HID, 4*HID])
__global__ void transpose_w(const float* __restrict__ W, float* __restrict__ Wt) {
    const int idx = blockIdx.x * 256 + threadIdx.x;  // tab*16384 + f*128 + h
    const int h   = idx & (HID - 1);
    const int f   = (idx >> 7) & (HID - 1);
    const int tab = idx >> 14;
    Wt[idx] = W[h * (4 * HID) + tab * HID + f];
}

// Kernel 1: T[tab][t][h] = sum_f pe_tab[t][f] * Wt[tab][f][h]  (+ b[h] for tab 0)
__global__ void precompute_tables(const float* __restrict__ pe_ss,
                                  const float* __restrict__ pe_se,
                                  const float* __restrict__ pe_es,
                                  const float* __restrict__ pe_ee,
                                  const float* __restrict__ Wt,
                                  const float* __restrict__ b,
                                  float* __restrict__ T) {
    const int t0  = blockIdx.x * TPB;
    const int tab = blockIdx.y;
    const int h   = threadIdx.x;

    const float* pe = (tab == 0) ? pe_ss : (tab == 1) ? pe_se
                    : (tab == 2) ? pe_es : pe_ee;

    const float* pr[TPB];
#pragma unroll
    for (int r = 0; r < TPB; ++r) {
        int tr = t0 + r; if (tr > TABLE - 1) tr = TABLE - 1;
        pr[r] = pe + (size_t)tr * HID;
    }

    float acc[TPB];
    const float binit = (tab == 0) ? b[h] : 0.0f;  // bias folded into T0 -> V
#pragma unroll
    for (int r = 0; r < TPB; ++r) acc[r] = binit;

    const float* wcol = Wt + ((size_t)tab * HID) * HID + h;  // lane-coalesced
#pragma unroll 4
    for (int f = 0; f < HID; ++f) {
        const float wf = wcol[(size_t)f * HID];
#pragma unroll
        for (int r = 0; r < TPB; ++r) acc[r] += pr[r][f] * wf;
    }

#pragma unroll
    for (int r = 0; r < TPB; ++r) {
        const int t = t0 + r;
        if (t < TABLE) T[((size_t)tab * TABLE + t) * HID + h] = acc[r];
    }
}

// Kernel 2: pairwise combine over sk (span_k in [0,7]):
//   V [sk][d][h] = bf16(T0[d][h] + T1[d-sk][h])   (b already in T0)
//   W2[sk][d][h] = bf16(T2[d][h] + T3[d-sk][h])
// d-sk < 0 clamped; those entries are provably never read (real i_se,i_ee >= 1).
__global__ void build_vw(const float* __restrict__ T,
                         ushort16* __restrict__ V,
                         ushort16* __restrict__ W2) {
    const int h  = threadIdx.x;
    const int d  = blockIdx.x;
    const int sk = blockIdx.y;
    int dm = d - sk; if (dm < 0) dm = 0;

    const size_t TR = (size_t)TABLE * HID;
    const float v = T[(size_t)d * HID + h] + T[TR     + (size_t)dm * HID + h];
    const float w = T[2 * TR + (size_t)d * HID + h] + T[3 * TR + (size_t)dm * HID + h];

    const size_t o = ((size_t)sk * TABLE + d) * HID + h;
    V[o]  = f2bf_rn(v);
    W2[o] = f2bf_rn(w);
}

// Kernel 3: out[b,q,k,h] = relu(V[sk][d][h] + W2[sk][d+sq][h])
//   sk = pe_k-ps_k, sq = pe_q-ps_q, d = ps_q-ps_k+SEQ
// One block per (q, b): pos row staged in LDS once; each thread loops 24
// k-values, 2x16B table loads (one full row per 16-lane group) + 2x16B NT
// stores per iter. 768 blocks instead of 36,864 -> per-block overhead
// amortized 48x; unroll 4 gives 8 global loads in flight per thread.
__global__ void gather_fuse3(const int* __restrict__ pos_s,
                             const int* __restrict__ pos_e,
                             const ushort16* __restrict__ V,
                             const ushort16* __restrict__ W2,
                             float* __restrict__ out) {
    __shared__ int sps[SEQ];
    __shared__ int spe[SEQ];

    const int q  = blockIdx.x;
    const int bb = blockIdx.y;

    for (int i = threadIdx.x; i < SEQ; i += 256) {
        sps[i] = pos_s[bb * SEQ + i];
        spe[i] = pos_e[bb * SEQ + i];
    }

    const int ps_q = pos_s[bb * SEQ + q];
    const int pe_q = pos_e[bb * SEQ + q];
    const int sq   = pe_q - ps_q;            // in [0,7]
    __syncthreads();

    const int h8 = threadIdx.x & 15;         // 16 lanes x 8 h-values = 128 h
    const int ks = threadIdx.x >> 4;         // 16 k-slots

    // one table row = 128 bf16 = 16 vuint4 (16 B each)
    const vuint4* Vv = (const vuint4*)V;
    const vuint4* Wv = (const vuint4*)W2;

    vfloat4* ob = (vfloat4*)out + ((size_t)bb * SEQ + q) * SEQ * 32;

#pragma unroll 4
    for (int k = ks; k < SEQ; k += 16) {
        const int sk = spe[k] - sps[k];      // in [0,7]
        const int d  = ps_q - sps[k] + SEQ;  // in [1,767]

        const vuint4 a = Vv[((size_t)sk * TABLE + d     ) * 16 + h8];
        const vuint4 c = Wv[((size_t)sk * TABLE + d + sq) * 16 + h8];

        vfloat4 r0, r1;
        r0.x = fmaxf(blo(a.x) + blo(c.x), 0.0f);
        r0.y = fmaxf(bhi(a.x) + bhi(c.x), 0.0f);
        r0.z = fmaxf(blo(a.y) + blo(c.y), 0.0f);
        r0.w = fmaxf(bhi(a.y) + bhi(c.y), 0.0f);
        r1.x = fmaxf(blo(a.z) + blo(c.z), 0.0f);
        r1.y = fmaxf(bhi(a.z) + bhi(c.z), 0.0f);
        r1.z = fmaxf(blo(a.w) + blo(c.w), 0.0f);
        r1.w = fmaxf(bhi(a.w) + bhi(c.w), 0.0f);

        vfloat4* op = ob + (size_t)k * 32 + h8 * 2;
        __builtin_nontemporal_store(r0, op);
        __builtin_nontemporal_store(r1, op + 1);
    }
}

extern "C" void kernel_launch(void* const* d_in, const int* in_sizes, int n_in,
                              void* d_out, int out_size, void* d_ws, size_t ws_size,
                              hipStream_t stream) {
    const int*   pos_s = (const int*)d_in[0];
    const int*   pos_e = (const int*)d_in[1];
    const float* pe_ss = (const float*)d_in[2];
    const float* pe_se = (const float*)d_in[3];
    const float* pe_es = (const float*)d_in[4];
    const float* pe_ee = (const float*)d_in[5];
    const float* W     = (const float*)d_in[6];
    const float* b     = (const float*)d_in[7];
    float*       out   = (float*)d_out;

    const size_t VW_ELEMS = (size_t)8 * TABLE * HID;         // per table
    ushort16* V  = (ushort16*)d_ws;
    ushort16* W2 = V + VW_ELEMS;
    float*    T  = (float*)(W2 + VW_ELEMS);
    float*    Wt = T + (size_t)4 * TABLE * HID;

    transpose_w<<<dim3((4 * HID * HID) / 256), 256, 0, stream>>>(W, Wt);

    precompute_tables<<<dim3((TABLE + TPB - 1) / TPB, 4), HID, 0, stream>>>(
        pe_ss, pe_se, pe_es, pe_ee, Wt, b, T);

    build_vw<<<dim3(TABLE, 8), HID, 0, stream>>>(T, V, W2);

    gather_fuse3<<<dim3(SEQ, BATCH), 256, 0, stream>>>(
        pos_s, pos_e, V, W2, out);
}

// Round 4
// 193.414 us; speedup vs baseline: 1.2131x; 1.2131x over previous
//
#include <hip/hip_runtime.h>

#define BATCH 2
#define SEQ   384
#define HID   128
#define TABLE (2 * SEQ + 1)   // 769
#define KPB   8               // k-values per block in gather kernel
#define TPB   8               // t-rows per block in precompute

typedef unsigned int   uint32;
typedef unsigned short ushort16;
typedef float  vfloat4 __attribute__((ext_vector_type(4)));
typedef uint32 vuint2  __attribute__((ext_vector_type(2)));

// ws layout:
//   V  (bf16) 8*TABLE*HID  = 1.50 MiB   bf16(T0[d] + T1[d-sk] + b)
//   W2 (bf16) 8*TABLE*HID  = 1.50 MiB   bf16(T2[d] + T3[d-sk])
//   T  (f32)  4*TABLE*HID  = 1.50 MiB   per-table GEMM results (f32 intermediate)
//   Wt (f32)  4*HID*HID    = 256 KiB
// V+W2 = 3.0 MiB -> fully L2-resident per XCD (4 MiB): gather reads at L2 tier.

// bf16 helpers: bf16 is the high half of fp32 — unpack is exact.
__device__ __forceinline__ float blo(uint32 u) { return __uint_as_float(u << 16); }
__device__ __forceinline__ float bhi(uint32 u) { return __uint_as_float(u & 0xFFFF0000u); }
__device__ __forceinline__ ushort16 f2bf_rn(float f) {
    uint32 u = __float_as_uint(f);
    u += 0x7FFFu + ((u >> 16) & 1u);   // round-to-nearest-even
    return (ushort16)(u >> 16);
}

// Kernel 0: Wt[tab][f][h] = W[h][tab*HID + f]   (W row-major [HID, 4*HID])
__global__ void transpose_w(const float* __restrict__ W, float* __restrict__ Wt) {
    const int idx = blockIdx.x * 256 + threadIdx.x;  // tab*16384 + f*128 + h
    const int h   = idx & (HID - 1);
    const int f   = (idx >> 7) & (HID - 1);
    const int tab = idx >> 14;
    Wt[idx] = W[h * (4 * HID) + tab * HID + f];
}

// Kernel 1: T[tab][t][h] = sum_f pe_tab[t][f] * Wt[tab][f][h]  (+ b[h] for tab 0)
__global__ void precompute_tables(const float* __restrict__ pe_ss,
                                  const float* __restrict__ pe_se,
                                  const float* __restrict__ pe_es,
                                  const float* __restrict__ pe_ee,
                                  const float* __restrict__ Wt,
                                  const float* __restrict__ b,
                                  float* __restrict__ T) {
    const int t0  = blockIdx.x * TPB;
    const int tab = blockIdx.y;
    const int h   = threadIdx.x;

    const float* pe = (tab == 0) ? pe_ss : (tab == 1) ? pe_se
                    : (tab == 2) ? pe_es : pe_ee;

    const float* pr[TPB];
#pragma unroll
    for (int r = 0; r < TPB; ++r) {
        int tr = t0 + r; if (tr > TABLE - 1) tr = TABLE - 1;
        pr[r] = pe + (size_t)tr * HID;
    }

    float acc[TPB];
    const float binit = (tab == 0) ? b[h] : 0.0f;  // bias folded into T0 -> V
#pragma unroll
    for (int r = 0; r < TPB; ++r) acc[r] = binit;

    const float* wcol = Wt + ((size_t)tab * HID) * HID + h;  // lane-coalesced
#pragma unroll 4
    for (int f = 0; f < HID; ++f) {
        const float wf = wcol[(size_t)f * HID];
#pragma unroll
        for (int r = 0; r < TPB; ++r) acc[r] += pr[r][f] * wf;
    }

#pragma unroll
    for (int r = 0; r < TPB; ++r) {
        const int t = t0 + r;
        if (t < TABLE) T[((size_t)tab * TABLE + t) * HID + h] = acc[r];
    }
}

// Kernel 2: pairwise combine over sk (span_k in [0,7]):
//   V [sk][d][h] = bf16(T0[d][h] + T1[d-sk][h])   (b already in T0)
//   W2[sk][d][h] = bf16(T2[d][h] + T3[d-sk][h])
// d-sk < 0 clamped; those entries are provably never read (real i_se,i_ee >= 1).
__global__ void build_vw(const float* __restrict__ T,
                         ushort16* __restrict__ V,
                         ushort16* __restrict__ W2) {
    const int h  = threadIdx.x;
    const int d  = blockIdx.x;
    const int sk = blockIdx.y;
    int dm = d - sk; if (dm < 0) dm = 0;

    const size_t TR = (size_t)TABLE * HID;
    const float v = T[(size_t)d * HID + h] + T[TR     + (size_t)dm * HID + h];
    const float w = T[2 * TR + (size_t)d * HID + h] + T[3 * TR + (size_t)dm * HID + h];

    const size_t o = ((size_t)sk * TABLE + d) * HID + h;
    V[o]  = f2bf_rn(v);
    W2[o] = f2bf_rn(w);
}

// Kernel 3: out[b,q,k,h] = relu(V[sk][d][h] + W2[sk][d+sq][h])
//   sk = pe_k-ps_k, sq = pe_q-ps_q, d = ps_q-ps_k+SEQ
// 2 L2-resident 8-byte loads + 1 PLAIN (cached, write-combining) float4 store.
// Single-variable experiment vs round 2: __builtin_nontemporal_store removed —
// theory is NT stores bypass L2 write-combining and throttle the 151 MB output
// stream well below the 6.3 TB/s the (normal-store) fill achieves.
__global__ void gather_fuse2(const int* __restrict__ pos_s,
                             const int* __restrict__ pos_e,
                             const ushort16* __restrict__ V,
                             const ushort16* __restrict__ W2,
                             float* __restrict__ out) {
    const int kk = threadIdx.x >> 5;
    const int h4 = threadIdx.x & 31;
    const int k  = blockIdx.x * KPB + kk;
    const int q  = blockIdx.y;
    const int bb = blockIdx.z;

    const int ps_q = pos_s[bb * SEQ + q];
    const int pe_q = pos_e[bb * SEQ + q];
    const int ps_k = pos_s[bb * SEQ + k];
    const int pe_k = pos_e[bb * SEQ + k];

    const int sq = pe_q - ps_q;              // in [0,7]
    const int sk = pe_k - ps_k;              // in [0,7]
    const int d  = ps_q - ps_k + SEQ;        // in [1,767]

    // one table row = 128 bf16 = 32 vuint2
    const vuint2* Vv = (const vuint2*)V;
    const vuint2* Wv = (const vuint2*)W2;

    const vuint2 a = Vv[((size_t)sk * TABLE + d     ) * 32 + h4];
    const vuint2 c = Wv[((size_t)sk * TABLE + d + sq) * 32 + h4];

    vfloat4 r;
    r.x = fmaxf(blo(a.x) + blo(c.x), 0.0f);
    r.y = fmaxf(bhi(a.x) + bhi(c.x), 0.0f);
    r.z = fmaxf(blo(a.y) + blo(c.y), 0.0f);
    r.w = fmaxf(bhi(a.y) + bhi(c.y), 0.0f);

    vfloat4* op = (vfloat4*)out + (((size_t)bb * SEQ + q) * SEQ + k) * 32 + h4;
    *op = r;
}

extern "C" void kernel_launch(void* const* d_in, const int* in_sizes, int n_in,
                              void* d_out, int out_size, void* d_ws, size_t ws_size,
                              hipStream_t stream) {
    const int*   pos_s = (const int*)d_in[0];
    const int*   pos_e = (const int*)d_in[1];
    const float* pe_ss = (const float*)d_in[2];
    const float* pe_se = (const float*)d_in[3];
    const float* pe_es = (const float*)d_in[4];
    const float* pe_ee = (const float*)d_in[5];
    const float* W     = (const float*)d_in[6];
    const float* b     = (const float*)d_in[7];
    float*       out   = (float*)d_out;

    const size_t VW_ELEMS = (size_t)8 * TABLE * HID;         // per table
    ushort16* V  = (ushort16*)d_ws;
    ushort16* W2 = V + VW_ELEMS;
    float*    T  = (float*)(W2 + VW_ELEMS);
    float*    Wt = T + (size_t)4 * TABLE * HID;

    transpose_w<<<dim3((4 * HID * HID) / 256), 256, 0, stream>>>(W, Wt);

    precompute_tables<<<dim3((TABLE + TPB - 1) / TPB, 4), HID, 0, stream>>>(
        pe_ss, pe_se, pe_es, pe_ee, Wt, b, T);

    build_vw<<<dim3(TABLE, 8), HID, 0, stream>>>(T, V, W2);

    gather_fuse2<<<dim3(SEQ / KPB, SEQ, BATCH), 256, 0, stream>>>(
        pos_s, pos_e, V, W2, out);
}